// Round 9
// baseline (2741.650 us; speedup 1.0000x reference)
//
#include <hip/hip_runtime.h>
#include <cstdint>
#include <cstddef>

#define BB 8
#define NN 8192
#define SS 2048
#define KNB 32

// Bit-exact squared distance matching numpy: (a-b) per component, squares,
// left-to-right sum, no FMA contraction.
__device__ __forceinline__ float sqdist_exact(float ax, float ay, float az,
                                              float bx, float by, float bz) {
#pragma clang fp contract(off)
    float dx = ax - bx;
    float dy = ay - by;
    float dz = az - bz;
    return (dx * dx + dy * dy) + dz * dz;
}

// DPP wave-64 reduce steps (gfx9 lineage: row_shr + row_bcast legal on CDNA4).
// old = identity, bound_ctrl=false -> invalid lanes contribute identity.
template <int CTRL>
__device__ __forceinline__ float dpp_fmax_step(float x) {
    int t = __builtin_amdgcn_update_dpp(__float_as_int(-1.0f), __float_as_int(x),
                                        CTRL, 0xf, 0xf, false);
    return fmaxf(x, __int_as_float(t));
}
template <int CTRL>
__device__ __forceinline__ int dpp_imin_step(int x) {
    int t = __builtin_amdgcn_update_dpp(0x7fffffff, x, CTRL, 0xf, 0xf, false);
    return min(x, t);
}
#define ROW_SHR1 0x111
#define ROW_SHR2 0x112
#define ROW_SHR4 0x114
#define ROW_SHR8 0x118
#define ROW_BC15 0x142
#define ROW_BC31 0x143

// full wave fmax reduce -> uniform value (via lane 63 readlane broadcast)
__device__ __forceinline__ float wave_fmax_uniform(float x) {
    x = dpp_fmax_step<ROW_SHR1>(x);
    x = dpp_fmax_step<ROW_SHR2>(x);
    x = dpp_fmax_step<ROW_SHR4>(x);
    x = dpp_fmax_step<ROW_SHR8>(x);
    x = dpp_fmax_step<ROW_BC15>(x);
    x = dpp_fmax_step<ROW_BC31>(x);
    return __int_as_float(__builtin_amdgcn_readlane(__float_as_int(x), 63));
}

// ---------------------------------------------------------------------------
// Weight transpose prep: w1T[c][64], w2T[j][64], w3T[j][128]
// ---------------------------------------------------------------------------
__global__ void prep_kernel(const float* __restrict__ w1, const float* __restrict__ w2,
                            const float* __restrict__ w3, float* __restrict__ w1T,
                            float* __restrict__ w2T, float* __restrict__ w3T) {
    for (int i = threadIdx.x; i < 192; i += 256) {
        int oc = i / 3, c = i % 3;
        w1T[c * 64 + oc] = w1[i];
    }
    for (int i = threadIdx.x; i < 4096; i += 256) {
        int oc = i >> 6, j = i & 63;
        w2T[j * 64 + oc] = w2[i];
    }
    for (int i = threadIdx.x; i < 8192; i += 256) {
        int oc = i >> 6, j = i & 63;
        w3T[j * 128 + oc] = w3[i];
    }
}

// spread 3-bit value to bit positions 0,3,6
__device__ __forceinline__ int part3(int v) {
    return (v & 1) | ((v & 2) << 2) | ((v & 4) << 4);
}

// (point index, quarter-group index) pairs: group g = i/4
#define PT_LIST2(X) X(0,0) X(1,0) X(2,0) X(3,0) X(4,1) X(5,1) X(6,1) X(7,1) \
                    X(8,2) X(9,2) X(10,2) X(11,2) X(12,3) X(13,3) X(14,3) X(15,3)
#define PT_LIST(X) X(0) X(1) X(2) X(3) X(4) X(5) X(6) X(7) \
                   X(8) X(9) X(10) X(11) X(12) X(13) X(14) X(15)
#define GRP_LIST(X) X(0) X(1) X(2) X(3)

// ---------------------------------------------------------------------------
// FPS: one block per batch, 512 threads (8 waves), 16 points/thread in named
// registers; amdgpu_waves_per_eu(2,2) forces the 256-VGPR budget (verified
// no-spill R7: VGPR=88, FETCH~978KB). NEW: each wave's Morton octant is split
// into 4 Morton-contiguous QUARTER-regions (256 pts, 4 pts/lane) with
// independent bboxes + cached max-dists -> 32 prune regions total (2x finer
// than the 1938us R2 config) at an 8-wave tail. Layout: Morton slot s stored
// at i*512 + t, i=4*((s>>8)&3)+((s>>6)&3), t=64*(s>>10)+(s&63), so lane l of
// wave w, point i covers quarter i/4 of octant w. Per iter: 4 cheap uniform
// prune checks; active quarters do a 4-pt update + DPP max-reduce; wave key
// recomputed only if something changed. Tail (best known): lane0 publishes
// key; all waves read 8 slots + compare chain; coords via readfirstlane +
// s_load; one barrier/iter (parity double-buffer).
// ---------------------------------------------------------------------------
__global__ __attribute__((amdgpu_flat_work_group_size(512, 512),
                          amdgpu_waves_per_eu(2, 2)))
void fps_kernel(const float* __restrict__ xyz_all,
                float4* __restrict__ wsSorted,
                float4* __restrict__ wsCtr,
                float* __restrict__ out0) {
    const int b = blockIdx.x;
    const float* xyz = xyz_all + (size_t)b * NN * 3;
    float4* sorted = wsSorted + (size_t)b * NN;
    float4* ctr = wsCtr + (size_t)b * SS;
    float* o0 = out0 + (size_t)b * 3 * SS;

    __shared__ int cellCnt[512];
    __shared__ int cellBase[512];
    __shared__ unsigned long long red[2][8];

    const int tid = threadIdx.x;
    const int wid = tid >> 6;
    const int lane = tid & 63;

    // --- pass 1: per-Morton-cell counts (16 pts/thread)
    cellCnt[tid] = 0;
    __syncthreads();
    int cellReg[16];
#pragma unroll
    for (int j = 0; j < 16; ++j) {
        int p = tid + j * 512;
        float x = xyz[p * 3 + 0], y = xyz[p * 3 + 1], z = xyz[p * 3 + 2];
        int qx = min(7, (int)(x * 8.0f));
        int qy = min(7, (int)(y * 8.0f));
        int qz = min(7, (int)(z * 8.0f));
        cellReg[j] = part3(qx) | (part3(qy) << 1) | (part3(qz) << 2);
        atomicAdd(&cellCnt[cellReg[j]], 1);
    }
    __syncthreads();
    int myCnt = cellCnt[tid];
    // inclusive Hillis-Steele scan over 512 cells (thread==cell)
    for (int off = 1; off < 512; off <<= 1) {
        int v = (tid >= off) ? cellCnt[tid - off] : 0;
        __syncthreads();
        cellCnt[tid] += v;
        __syncthreads();
    }
    cellBase[tid] = cellCnt[tid] - myCnt;
    __syncthreads();
    // --- pass 2: scatter to global ws. Morton slot s -> address i*512 + t
    // with i = 4*((s>>8)&3)+((s>>6)&3), t = 64*(s>>10)+(s&63): quarter g of
    // wave w is Morton-contiguous AND read-back sorted[i*512+tid] coalesces.
#pragma unroll
    for (int j = 0; j < 16; ++j) {
        int p = tid + j * 512;
        float x = xyz[p * 3 + 0], y = xyz[p * 3 + 1], z = xyz[p * 3 + 2];
        int pos = atomicAdd(&cellBase[cellReg[j]], 1);
        int i = 4 * ((pos >> 8) & 3) + ((pos >> 6) & 3);
        int t = ((pos >> 10) << 6) + (pos & 63);
        sorted[i * 512 + t] = make_float4(x, y, z, __int_as_float(p));
    }
    __threadfence();
    __syncthreads();

    // --- load own 16 points into named registers + per-quarter bboxes
#define DECL_BBOX(g)                                      \
    float lox##g = 1e30f, loy##g = 1e30f, loz##g = 1e30f, \
          hix##g = -1e30f, hiy##g = -1e30f, hiz##g = -1e30f;
    GRP_LIST(DECL_BBOX)

#define DECL_PT(i, g)                       \
    float px##i, py##i, pz##i, dist##i;     \
    int od##i;                              \
    {                                       \
        float4 v = sorted[i * 512 + tid];   \
        px##i = v.x; py##i = v.y; pz##i = v.z; \
        od##i = __float_as_int(v.w);        \
        dist##i = 1e10f;                    \
        lox##g = fminf(lox##g, v.x); hix##g = fmaxf(hix##g, v.x); \
        loy##g = fminf(loy##g, v.y); hiy##g = fmaxf(hiy##g, v.y); \
        loz##g = fminf(loz##g, v.z); hiz##g = fmaxf(hiz##g, v.z); \
    }
    PT_LIST2(DECL_PT)

    // per-quarter wave bbox via shfl butterfly (init only, not the hot path)
#define BBOX_RED(g)                                            \
    {                                                          \
        for (int off = 1; off < 64; off <<= 1) {               \
            lox##g = fminf(lox##g, __shfl_xor(lox##g, off));   \
            loy##g = fminf(loy##g, __shfl_xor(loy##g, off));   \
            loz##g = fminf(loz##g, __shfl_xor(loz##g, off));   \
            hix##g = fmaxf(hix##g, __shfl_xor(hix##g, off));   \
            hiy##g = fmaxf(hiy##g, __shfl_xor(hiy##g, off));   \
            hiz##g = fmaxf(hiz##g, __shfl_xor(hiz##g, off));   \
        }                                                      \
    }
    GRP_LIST(BBOX_RED)

    float cx = xyz[0], cy = xyz[1], cz = xyz[2];
    if (tid == 0) {
        o0[0] = cx; o0[SS] = cy; o0[2 * SS] = cz;
        ctr[0] = make_float4(cx, cy, cz, 0.0f);
    }

    unsigned long long waveKey =
        ((unsigned long long)__float_as_uint(1e10f) << 32) | 0xFFFFFFFFull;
    float bv0 = 1e10f, bv1 = 1e10f, bv2 = 1e10f, bv3 = 1e10f;  // quarter maxes

    for (int s = 1; s < SS; ++s) {
        const int par = s & 1;
        // per-quarter exact lower bounds (wave-uniform values)
#define PRUNE_G(g)                                                     \
        float lbq##g;                                                  \
        {                                                              \
            float ddx = fmaxf(fmaxf(lox##g - cx, cx - hix##g), 0.0f);  \
            float ddy = fmaxf(fmaxf(loy##g - cy, cy - hiy##g), 0.0f);  \
            float ddz = fmaxf(fmaxf(loz##g - cz, cz - hiz##g), 0.0f);  \
            lbq##g = ddx * ddx + ddy * ddy + ddz * ddz;                \
        }
        GRP_LIST(PRUNE_G)

        bool changed = false;
#define UPD_PT(i)                                                        \
    {                                                                    \
        float d = sqdist_exact(px##i, py##i, pz##i, cx, cy, cz);         \
        dist##i = fminf(dist##i, d);                                     \
        nm = fmaxf(nm, dist##i);                                         \
    }
#define UPD_G(g, i0, i1, i2, i3)                     \
        if (lbq##g * 0.999f < bv##g) {               \
            float nm = -1.0f;                        \
            UPD_PT(i0) UPD_PT(i1) UPD_PT(i2) UPD_PT(i3) \
            bv##g = wave_fmax_uniform(nm);           \
            changed = true;                          \
        }
        UPD_G(0, 0, 1, 2, 3)
        UPD_G(1, 4, 5, 6, 7)
        UPD_G(2, 8, 9, 10, 11)
        UPD_G(3, 12, 13, 14, 15)

        if (changed) {
            float wv = fmaxf(fmaxf(bv0, bv1), fmaxf(bv2, bv3));
            // first-orig-index among exact max holders (16 pts)
            int cand = 0x7fffffff;
#define IDX_PT(i) cand = (dist##i == wv) ? min(cand, od##i) : cand;
            PT_LIST(IDX_PT)
            cand = dpp_imin_step<ROW_SHR1>(cand);
            cand = dpp_imin_step<ROW_SHR2>(cand);
            cand = dpp_imin_step<ROW_SHR4>(cand);
            cand = dpp_imin_step<ROW_SHR8>(cand);
            cand = dpp_imin_step<ROW_BC15>(cand);
            cand = dpp_imin_step<ROW_BC31>(cand);
            int wiw = __builtin_amdgcn_readlane(cand, 63);
            waveKey = ((unsigned long long)__float_as_uint(wv) << 32) |
                      (unsigned)(~(unsigned)wiw);
        }
        if (lane == 0) red[par][wid] = waveKey;
        __syncthreads();
        unsigned long long best = red[par][0];
#pragma unroll
        for (int k = 1; k < 8; ++k) {
            unsigned long long o = red[par][k];
            best = (o > best) ? o : best;
        }
        int wi = (int)(~(unsigned)best);
        int wiu = __builtin_amdgcn_readfirstlane(wi);
        cx = xyz[wiu * 3 + 0];  // scalar broadcast load (s_load)
        cy = xyz[wiu * 3 + 1];
        cz = xyz[wiu * 3 + 2];
        if (tid == 0) {
            o0[s] = cx; o0[SS + s] = cy; o0[2 * SS + s] = cz;
            ctr[s] = make_float4(cx, cy, cz, 0.0f);
        }
    }
}

// ---------------------------------------------------------------------------
// Fused ball-query + MLP + maxpool. Block = 128 threads (2 waves), 2 centers.
// ---------------------------------------------------------------------------
__global__ __launch_bounds__(128) void bqmlp_kernel(const float* __restrict__ xyz_all,
                                                    const float4* __restrict__ wsCtr,
                                                    const float* __restrict__ w1T,
                                                    const float* __restrict__ b1,
                                                    const float* __restrict__ w2T,
                                                    const float* __restrict__ b2,
                                                    const float* __restrict__ w3T,
                                                    const float* __restrict__ b3,
                                                    float* __restrict__ out1) {
    const int b = blockIdx.x >> 10;            // 1024 blocks per batch
    const int s0 = (blockIdx.x & 1023) * 2;    // 2 centers per block
    const float* xyz = xyz_all + (size_t)b * NN * 3;

    __shared__ float relF[2 * KNB * 3];  // [64 rows][3]
    __shared__ float h1T[64 * 64];       // [ch][row]
    __shared__ float h2T[64 * 64];       // [ch][row]

    const int tid = threadIdx.x;
    const int cb = __builtin_amdgcn_readfirstlane(tid >> 6);  // wave id (uniform)
    const int l = tid & 63;

    // ---- ball query: wave cb handles center s0+cb
    {
        float4 cc = wsCtr[(size_t)b * SS + s0 + cb];
        float ccx = cc.x, ccy = cc.y, ccz = cc.z;
        const float R2 = (float)(0.2 * 0.2);
        int total = 0;
        float fx = 0.f, fy = 0.f, fz = 0.f;
        bool have = false;
        for (int chunk = 0; chunk < 128 && total < KNB; ++chunk) {
            int p = chunk * 64 + l;
            float x = xyz[p * 3 + 0], y = xyz[p * 3 + 1], z = xyz[p * 3 + 2];
            float d = sqdist_exact(ccx, ccy, ccz, x, y, z);
            bool hit = (d <= R2);
            unsigned long long mask = __ballot(hit);
            int cnt = __popcll(mask);
            if (cnt) {
                int pos = total + __popcll(mask & ((1ull << l) - 1ull));
                float rx = x - ccx, ry = y - ccy, rz = z - ccz;  // single subs: exact
                if (hit && pos < KNB) {
                    relF[(cb * KNB + pos) * 3 + 0] = rx;
                    relF[(cb * KNB + pos) * 3 + 1] = ry;
                    relF[(cb * KNB + pos) * 3 + 2] = rz;
                }
                if (hit && pos == 0) { fx = rx; fy = ry; fz = rz; have = true; }
                total += cnt;
            }
        }
        unsigned long long hm = __ballot(have);
        if (total < KNB) {
            int src = __ffsll((long long)hm) - 1;
            float gx = __shfl(fx, src), gy = __shfl(fy, src), gz = __shfl(fz, src);
            if (l >= total && l < KNB) {
                relF[(cb * KNB + l) * 3 + 0] = gx;
                relF[(cb * KNB + l) * 3 + 1] = gy;
                relF[(cb * KNB + l) * 3 + 2] = gz;
            }
        }
    }
    __syncthreads();

    const int r = l;  // row 0..63: rows 0..31 center s0, rows 32..63 center s0+1

    // ---- layer 1: rel(3) -> 64, thread covers ch block cb*32..+31 for row r
    {
        float rx = relF[r * 3 + 0], ry = relF[r * 3 + 1], rz = relF[r * 3 + 2];
#pragma unroll
        for (int i = 0; i < 32; ++i) {
            int ch = cb * 32 + i;
            float h = b1[ch];
            h = fmaf(rx, w1T[0 * 64 + ch], h);
            h = fmaf(ry, w1T[1 * 64 + ch], h);
            h = fmaf(rz, w1T[2 * 64 + ch], h);
            h1T[ch * 64 + r] = fmaxf(h, 0.0f);
        }
    }
    __syncthreads();

    // ---- layer 2: 64 -> 64
    {
        float acc[32];
#pragma unroll
        for (int i = 0; i < 32; ++i) acc[i] = b2[cb * 32 + i];
#pragma unroll 4
        for (int j = 0; j < 64; ++j) {
            float a = h1T[j * 64 + r];
            const float* wrow = w2T + j * 64 + cb * 32;
#pragma unroll
            for (int i = 0; i < 32; ++i) acc[i] = fmaf(a, wrow[i], acc[i]);
        }
#pragma unroll
        for (int i = 0; i < 32; ++i) h2T[(cb * 32 + i) * 64 + r] = fmaxf(acc[i], 0.0f);
    }
    __syncthreads();

    // ---- layer 3: 64 -> 128, fused relu + maxpool over the 32 rows/center
    {
        float acc[64];
#pragma unroll
        for (int i = 0; i < 64; ++i) acc[i] = b3[cb * 64 + i];
#pragma unroll 2
        for (int j = 0; j < 64; ++j) {
            float a = h2T[j * 64 + r];
            const float* wrow = w3T + j * 128 + cb * 64;
#pragma unroll
            for (int i = 0; i < 64; ++i) acc[i] = fmaf(a, wrow[i], acc[i]);
        }
#pragma unroll
        for (int i = 0; i < 64; ++i) {
            float v = fmaxf(acc[i], 0.0f);
            v = fmaxf(v, __shfl_xor(v, 1));
            v = fmaxf(v, __shfl_xor(v, 2));
            v = fmaxf(v, __shfl_xor(v, 4));
            v = fmaxf(v, __shfl_xor(v, 8));
            v = fmaxf(v, __shfl_xor(v, 16));
            acc[i] = v;
        }
        if ((l & 31) == 0) {
            int sA = s0 + (l >> 5);
            float* op = out1 + ((size_t)b * 128 + cb * 64) * SS + sA;
#pragma unroll
            for (int i = 0; i < 64; ++i) op[(size_t)i * SS] = acc[i];
        }
    }
}

extern "C" void kernel_launch(void* const* d_in, const int* in_sizes, int n_in,
                              void* d_out, int out_size, void* d_ws, size_t ws_size,
                              hipStream_t stream) {
    (void)in_sizes; (void)n_in; (void)out_size; (void)ws_size;
    const float* xyz = (const float*)d_in[0];
    // d_in[1] = features : unused by the reference
    const float* w1 = (const float*)d_in[2];
    const float* b1 = (const float*)d_in[3];
    const float* w2 = (const float*)d_in[4];
    const float* b2 = (const float*)d_in[5];
    const float* w3 = (const float*)d_in[6];
    const float* b3 = (const float*)d_in[7];
    float* out = (float*)d_out;

    // workspace layout
    float4* wsCtr = (float4*)d_ws;              // B*S float4      (256 KB)
    float4* wsSorted = wsCtr + BB * SS;         // B*N float4      (1 MB)
    float* w1T = (float*)(wsSorted + BB * NN);  // 192 f
    float* w2T = w1T + 192;                     // 4096 f
    float* w3T = w2T + 4096;                    // 8192 f

    prep_kernel<<<1, 256, 0, stream>>>(w1, w2, w3, w1T, w2T, w3T);
    fps_kernel<<<BB, 512, 0, stream>>>(xyz, wsSorted, wsCtr, out);
    bqmlp_kernel<<<BB * (SS / 2), 128, 0, stream>>>(xyz, wsCtr, w1T, b1, w2T, b2,
                                                    w3T, b3, out + BB * 3 * SS);
}

// Round 10
// 2218.718 us; speedup vs baseline: 1.2357x; 1.2357x over previous
//
#include <hip/hip_runtime.h>
#include <cstdint>
#include <cstddef>

#define BB 8
#define NN 8192
#define SS 2048
#define KNB 32

// Bit-exact squared distance matching numpy: (a-b) per component, squares,
// left-to-right sum, no FMA contraction.
__device__ __forceinline__ float sqdist_exact(float ax, float ay, float az,
                                              float bx, float by, float bz) {
#pragma clang fp contract(off)
    float dx = ax - bx;
    float dy = ay - by;
    float dz = az - bz;
    return (dx * dx + dy * dy) + dz * dz;
}

// DPP wave-64 reduce steps (gfx9 lineage: row_shr + row_bcast legal on CDNA4).
// old = identity, bound_ctrl=false -> invalid lanes contribute identity.
template <int CTRL>
__device__ __forceinline__ float dpp_fmax_step(float x) {
    int t = __builtin_amdgcn_update_dpp(__float_as_int(-1.0f), __float_as_int(x),
                                        CTRL, 0xf, 0xf, false);
    return fmaxf(x, __int_as_float(t));
}
template <int CTRL>
__device__ __forceinline__ int dpp_imin_step(int x) {
    int t = __builtin_amdgcn_update_dpp(0x7fffffff, x, CTRL, 0xf, 0xf, false);
    return min(x, t);
}
#define ROW_SHR1 0x111
#define ROW_SHR2 0x112
#define ROW_SHR4 0x114
#define ROW_SHR8 0x118
#define ROW_BC15 0x142
#define ROW_BC31 0x143

// ---------------------------------------------------------------------------
// Weight transpose prep: w1T[c][64], w2T[j][64], w3T[j][128]
// ---------------------------------------------------------------------------
__global__ void prep_kernel(const float* __restrict__ w1, const float* __restrict__ w2,
                            const float* __restrict__ w3, float* __restrict__ w1T,
                            float* __restrict__ w2T, float* __restrict__ w3T) {
    for (int i = threadIdx.x; i < 192; i += 256) {
        int oc = i / 3, c = i % 3;
        w1T[c * 64 + oc] = w1[i];
    }
    for (int i = threadIdx.x; i < 4096; i += 256) {
        int oc = i >> 6, j = i & 63;
        w2T[j * 64 + oc] = w2[i];
    }
    for (int i = threadIdx.x; i < 8192; i += 256) {
        int oc = i >> 6, j = i & 63;
        w3T[j * 128 + oc] = w3[i];
    }
}

// spread 3-bit value to bit positions 0,3,6
__device__ __forceinline__ int part3(int v) {
    return (v & 1) | ((v & 2) << 2) | ((v & 4) << 4);
}

#define PT_LIST(X) X(0) X(1) X(2) X(3) X(4) X(5) X(6) X(7) \
                   X(8) X(9) X(10) X(11) X(12) X(13) X(14) X(15)

// ---------------------------------------------------------------------------
// FPS — EXACT R7 configuration (verified best: 1891 us, VGPR=88, no spill).
// One block per batch, 512 threads (8 waves), 16 points/thread in named
// registers; amdgpu_waves_per_eu(2,2) forces the 256-VGPR budget. Morton sort
// -> wave-uniform exact bbox prune (one octant per wave); DPP argmax in-wave;
// lane0 publishes key; all waves read the 8 slots with a compare chain;
// winner coords via readfirstlane + s_load broadcast; one barrier/iter.
// ---------------------------------------------------------------------------
__global__ __attribute__((amdgpu_flat_work_group_size(512, 512),
                          amdgpu_waves_per_eu(2, 2)))
void fps_kernel(const float* __restrict__ xyz_all,
                float4* __restrict__ wsSorted,
                float4* __restrict__ wsCtr,
                float* __restrict__ out0) {
    const int b = blockIdx.x;
    const float* xyz = xyz_all + (size_t)b * NN * 3;
    float4* sorted = wsSorted + (size_t)b * NN;
    float4* ctr = wsCtr + (size_t)b * SS;
    float* o0 = out0 + (size_t)b * 3 * SS;

    __shared__ int cellCnt[512];
    __shared__ int cellBase[512];
    __shared__ unsigned long long red[2][8];

    const int tid = threadIdx.x;
    const int wid = tid >> 6;
    const int lane = tid & 63;

    // --- pass 1: per-Morton-cell counts (16 pts/thread)
    cellCnt[tid] = 0;
    __syncthreads();
    int cellReg[16];
#pragma unroll
    for (int j = 0; j < 16; ++j) {
        int p = tid + j * 512;
        float x = xyz[p * 3 + 0], y = xyz[p * 3 + 1], z = xyz[p * 3 + 2];
        int qx = min(7, (int)(x * 8.0f));
        int qy = min(7, (int)(y * 8.0f));
        int qz = min(7, (int)(z * 8.0f));
        cellReg[j] = part3(qx) | (part3(qy) << 1) | (part3(qz) << 2);
        atomicAdd(&cellCnt[cellReg[j]], 1);
    }
    __syncthreads();
    int myCnt = cellCnt[tid];
    // inclusive Hillis-Steele scan over 512 cells (thread==cell)
    for (int off = 1; off < 512; off <<= 1) {
        int v = (tid >= off) ? cellCnt[tid - off] : 0;
        __syncthreads();
        cellCnt[tid] += v;
        __syncthreads();
    }
    cellBase[tid] = cellCnt[tid] - myCnt;
    __syncthreads();
    // --- pass 2: scatter to global ws. Slot s stored at (s&15)*512 + (s>>4)
    // so read-back (thread t owns Morton slots 16t..16t+15) is coalesced.
#pragma unroll
    for (int j = 0; j < 16; ++j) {
        int p = tid + j * 512;
        float x = xyz[p * 3 + 0], y = xyz[p * 3 + 1], z = xyz[p * 3 + 2];
        int pos = atomicAdd(&cellBase[cellReg[j]], 1);
        sorted[(pos & 15) * 512 + (pos >> 4)] = make_float4(x, y, z, __int_as_float(p));
    }
    __threadfence();
    __syncthreads();

    // --- load own 16 Morton-contiguous points into named registers + lane bbox
    float lox = 1e30f, loy = 1e30f, loz = 1e30f;
    float hix = -1e30f, hiy = -1e30f, hiz = -1e30f;
#define DECL_PT(i)                          \
    float px##i, py##i, pz##i, dist##i;     \
    int od##i;                              \
    {                                       \
        float4 v = sorted[i * 512 + tid];   \
        px##i = v.x; py##i = v.y; pz##i = v.z; \
        od##i = __float_as_int(v.w);        \
        dist##i = 1e10f;                    \
        lox = fminf(lox, v.x); hix = fmaxf(hix, v.x); \
        loy = fminf(loy, v.y); hiy = fmaxf(hiy, v.y); \
        loz = fminf(loz, v.z); hiz = fmaxf(hiz, v.z); \
    }
    PT_LIST(DECL_PT)

    // wave bbox via one-time shfl butterfly (not on the hot path)
    float wlox = lox, wloy = loy, wloz = loz, whix = hix, whiy = hiy, whiz = hiz;
#pragma unroll
    for (int off = 1; off < 64; off <<= 1) {
        wlox = fminf(wlox, __shfl_xor(wlox, off));
        wloy = fminf(wloy, __shfl_xor(wloy, off));
        wloz = fminf(wloz, __shfl_xor(wloz, off));
        whix = fmaxf(whix, __shfl_xor(whix, off));
        whiy = fmaxf(whiy, __shfl_xor(whiy, off));
        whiz = fmaxf(whiz, __shfl_xor(whiz, off));
    }

    float cx = xyz[0], cy = xyz[1], cz = xyz[2];
    if (tid == 0) {
        o0[0] = cx; o0[SS] = cy; o0[2 * SS] = cz;
        ctr[0] = make_float4(cx, cy, cz, 0.0f);
    }

    unsigned long long waveKey =
        ((unsigned long long)__float_as_uint(1e10f) << 32) | 0xFFFFFFFFull;
    float wave_bv = 1e10f;  // max min-dist over this wave's 1024 points (cached)

    for (int s = 1; s < SS; ++s) {
        const int par = s & 1;
        // wave-uniform exact prune: if lb >= wave max dist, no dist can change
        float ddx = fmaxf(fmaxf(wlox - cx, cx - whix), 0.0f);
        float ddy = fmaxf(fmaxf(wloy - cy, cy - whiy), 0.0f);
        float ddz = fmaxf(fmaxf(wloz - cz, cz - whiz), 0.0f);
        float lb2 = ddx * ddx + ddy * ddy + ddz * ddz;
        if (lb2 * 0.999f < wave_bv) {
            float nbv = -1.0f;
#define UPD_PT(i)                                                        \
    {                                                                    \
        float d = sqdist_exact(px##i, py##i, pz##i, cx, cy, cz);         \
        dist##i = fminf(dist##i, d);                                     \
        nbv = fmaxf(nbv, dist##i);                                       \
    }
            PT_LIST(UPD_PT)
            // wave max value via DPP (VALU-speed), result in lane 63
            float m = nbv;
            m = dpp_fmax_step<ROW_SHR1>(m);
            m = dpp_fmax_step<ROW_SHR2>(m);
            m = dpp_fmax_step<ROW_SHR4>(m);
            m = dpp_fmax_step<ROW_SHR8>(m);
            m = dpp_fmax_step<ROW_BC15>(m);
            m = dpp_fmax_step<ROW_BC31>(m);
            float wv = __int_as_float(__builtin_amdgcn_readlane(__float_as_int(m), 63));
            // first-orig-index among exact max holders
            int cand = 0x7fffffff;
#define IDX_PT(i) cand = (dist##i == wv) ? min(cand, od##i) : cand;
            PT_LIST(IDX_PT)
            cand = dpp_imin_step<ROW_SHR1>(cand);
            cand = dpp_imin_step<ROW_SHR2>(cand);
            cand = dpp_imin_step<ROW_SHR4>(cand);
            cand = dpp_imin_step<ROW_SHR8>(cand);
            cand = dpp_imin_step<ROW_BC15>(cand);
            cand = dpp_imin_step<ROW_BC31>(cand);
            int wiw = __builtin_amdgcn_readlane(cand, 63);
            waveKey = ((unsigned long long)__float_as_uint(wv) << 32) |
                      (unsigned)(~(unsigned)wiw);
            wave_bv = wv;
        }
        if (lane == 0) red[par][wid] = waveKey;
        __syncthreads();
        unsigned long long best = red[par][0];
#pragma unroll
        for (int k = 1; k < 8; ++k) {
            unsigned long long o = red[par][k];
            best = (o > best) ? o : best;
        }
        int wi = (int)(~(unsigned)best);
        int wiu = __builtin_amdgcn_readfirstlane(wi);
        cx = xyz[wiu * 3 + 0];  // scalar broadcast load (s_load)
        cy = xyz[wiu * 3 + 1];
        cz = xyz[wiu * 3 + 2];
        if (tid == 0) {
            o0[s] = cx; o0[SS + s] = cy; o0[2 * SS + s] = cz;
            ctr[s] = make_float4(cx, cy, cz, 0.0f);
        }
    }
}

// ---------------------------------------------------------------------------
// Fused ball-query + MLP + maxpool. Block = 128 threads (2 waves), 2 centers.
// LDS HALVED vs prior rounds: h2 reuses h1's buffer (compute layer-2 accs
// from h1, barrier, overwrite in place, barrier). 33KB -> ~17KB per block ->
// ~9 blocks/CU LDS-wise (was 4) => ~2x waves/CU to hide LDS/VALU latency.
// ---------------------------------------------------------------------------
__global__ __launch_bounds__(128) void bqmlp_kernel(const float* __restrict__ xyz_all,
                                                    const float4* __restrict__ wsCtr,
                                                    const float* __restrict__ w1T,
                                                    const float* __restrict__ b1,
                                                    const float* __restrict__ w2T,
                                                    const float* __restrict__ b2,
                                                    const float* __restrict__ w3T,
                                                    const float* __restrict__ b3,
                                                    float* __restrict__ out1) {
    const int b = blockIdx.x >> 10;            // 1024 blocks per batch
    const int s0 = (blockIdx.x & 1023) * 2;    // 2 centers per block
    const float* xyz = xyz_all + (size_t)b * NN * 3;

    __shared__ float relF[2 * KNB * 3];  // [64 rows][3]
    __shared__ float hT[64 * 64];        // [ch][row] — holds h1, then h2

    const int tid = threadIdx.x;
    const int cb = __builtin_amdgcn_readfirstlane(tid >> 6);  // wave id (uniform)
    const int l = tid & 63;

    // ---- ball query: wave cb handles center s0+cb
    {
        float4 cc = wsCtr[(size_t)b * SS + s0 + cb];
        float ccx = cc.x, ccy = cc.y, ccz = cc.z;
        const float R2 = (float)(0.2 * 0.2);
        int total = 0;
        float fx = 0.f, fy = 0.f, fz = 0.f;
        bool have = false;
        for (int chunk = 0; chunk < 128 && total < KNB; ++chunk) {
            int p = chunk * 64 + l;
            float x = xyz[p * 3 + 0], y = xyz[p * 3 + 1], z = xyz[p * 3 + 2];
            float d = sqdist_exact(ccx, ccy, ccz, x, y, z);
            bool hit = (d <= R2);
            unsigned long long mask = __ballot(hit);
            int cnt = __popcll(mask);
            if (cnt) {
                int pos = total + __popcll(mask & ((1ull << l) - 1ull));
                float rx = x - ccx, ry = y - ccy, rz = z - ccz;  // single subs: exact
                if (hit && pos < KNB) {
                    relF[(cb * KNB + pos) * 3 + 0] = rx;
                    relF[(cb * KNB + pos) * 3 + 1] = ry;
                    relF[(cb * KNB + pos) * 3 + 2] = rz;
                }
                if (hit && pos == 0) { fx = rx; fy = ry; fz = rz; have = true; }
                total += cnt;
            }
        }
        unsigned long long hm = __ballot(have);
        if (total < KNB) {
            int src = __ffsll((long long)hm) - 1;
            float gx = __shfl(fx, src), gy = __shfl(fy, src), gz = __shfl(fz, src);
            if (l >= total && l < KNB) {
                relF[(cb * KNB + l) * 3 + 0] = gx;
                relF[(cb * KNB + l) * 3 + 1] = gy;
                relF[(cb * KNB + l) * 3 + 2] = gz;
            }
        }
    }
    __syncthreads();

    const int r = l;  // row 0..63: rows 0..31 center s0, rows 32..63 center s0+1

    // ---- layer 1: rel(3) -> 64, thread covers ch block cb*32..+31 for row r
    {
        float rx = relF[r * 3 + 0], ry = relF[r * 3 + 1], rz = relF[r * 3 + 2];
#pragma unroll
        for (int i = 0; i < 32; ++i) {
            int ch = cb * 32 + i;
            float h = b1[ch];
            h = fmaf(rx, w1T[0 * 64 + ch], h);
            h = fmaf(ry, w1T[1 * 64 + ch], h);
            h = fmaf(rz, w1T[2 * 64 + ch], h);
            hT[ch * 64 + r] = fmaxf(h, 0.0f);
        }
    }
    __syncthreads();

    // ---- layer 2: 64 -> 64 (reads h1 from hT; after barrier, h2 overwrites)
    {
        float acc[32];
#pragma unroll
        for (int i = 0; i < 32; ++i) acc[i] = b2[cb * 32 + i];
#pragma unroll 4
        for (int j = 0; j < 64; ++j) {
            float a = hT[j * 64 + r];
            const float* wrow = w2T + j * 64 + cb * 32;
#pragma unroll
            for (int i = 0; i < 32; ++i) acc[i] = fmaf(a, wrow[i], acc[i]);
        }
        __syncthreads();  // all h1 reads complete before overwrite
#pragma unroll
        for (int i = 0; i < 32; ++i) hT[(cb * 32 + i) * 64 + r] = fmaxf(acc[i], 0.0f);
    }
    __syncthreads();

    // ---- layer 3: 64 -> 128, fused relu + maxpool over the 32 rows/center
    {
        float acc[64];
#pragma unroll
        for (int i = 0; i < 64; ++i) acc[i] = b3[cb * 64 + i];
#pragma unroll 2
        for (int j = 0; j < 64; ++j) {
            float a = hT[j * 64 + r];
            const float* wrow = w3T + j * 128 + cb * 64;
#pragma unroll
            for (int i = 0; i < 64; ++i) acc[i] = fmaf(a, wrow[i], acc[i]);
        }
#pragma unroll
        for (int i = 0; i < 64; ++i) {
            float v = fmaxf(acc[i], 0.0f);
            v = fmaxf(v, __shfl_xor(v, 1));
            v = fmaxf(v, __shfl_xor(v, 2));
            v = fmaxf(v, __shfl_xor(v, 4));
            v = fmaxf(v, __shfl_xor(v, 8));
            v = fmaxf(v, __shfl_xor(v, 16));
            acc[i] = v;
        }
        if ((l & 31) == 0) {
            int sA = s0 + (l >> 5);
            float* op = out1 + ((size_t)b * 128 + cb * 64) * SS + sA;
#pragma unroll
            for (int i = 0; i < 64; ++i) op[(size_t)i * SS] = acc[i];
        }
    }
}

extern "C" void kernel_launch(void* const* d_in, const int* in_sizes, int n_in,
                              void* d_out, int out_size, void* d_ws, size_t ws_size,
                              hipStream_t stream) {
    (void)in_sizes; (void)n_in; (void)out_size; (void)ws_size;
    const float* xyz = (const float*)d_in[0];
    // d_in[1] = features : unused by the reference
    const float* w1 = (const float*)d_in[2];
    const float* b1 = (const float*)d_in[3];
    const float* w2 = (const float*)d_in[4];
    const float* b2 = (const float*)d_in[5];
    const float* w3 = (const float*)d_in[6];
    const float* b3 = (const float*)d_in[7];
    float* out = (float*)d_out;

    // workspace layout
    float4* wsCtr = (float4*)d_ws;              // B*S float4      (256 KB)
    float4* wsSorted = wsCtr + BB * SS;         // B*N float4      (1 MB)
    float* w1T = (float*)(wsSorted + BB * NN);  // 192 f
    float* w2T = w1T + 192;                     // 4096 f
    float* w3T = w2T + 4096;                    // 8192 f

    prep_kernel<<<1, 256, 0, stream>>>(w1, w2, w3, w1T, w2T, w3T);
    fps_kernel<<<BB, 512, 0, stream>>>(xyz, wsSorted, wsCtr, out);
    bqmlp_kernel<<<BB * (SS / 2), 128, 0, stream>>>(xyz, wsCtr, w1T, b1, w2T, b2,
                                                    w3T, b3, out + BB * 3 * SS);
}